// Round 4
// baseline (129.576 us; speedup 1.0000x reference)
//
#include <hip/hip_runtime.h>
#include <hip/hip_bf16.h>

// Problem: V=50000, D=300, B=8, Q=128, W=16, L=8192
//   q_e[bq]   = sum_w emb[queries[bq,w]] / count(queries[bq,w]!=0)
//   sim[bq,l] = dot(q_e[bq], emb[labels[l]]) / max(|q_e[bq]|*|emb[labels[l]]|, 1e-8)
//   mask[bq,l]= (count!=0) && (labels[l]!=0)
// dtypes: emb float32, indices int32 (harness-converted), out float32.
// Output: sim (8,128,1,8192) then mask (8,128,1,8192) = 16,777,216 floats.
//
// History: R6 packed layout 153.9->129.7. R7 LDS-staged qe + dbl-buf a-frags
// = 125.8 (best). R8 FAILED 133.8: full prefetch -> 200 VGPR -> occupancy
// cliff. R9 XCD swizzle NEUTRAL 126.4. R10 64x64 tile + 2-gen grid: 128.2
// (slightly worse). Lesson: occupancy/locality are NOT binding; stop there.
// R11 (this): attack the SERIAL part instead. Each block's prologue
// (10x global_load_lds -> vmcnt(0) -> barrier) is the one hard stall, and
// the staging is unnecessary: qep is 640KB, L2-hot (just written by build),
// and the packed layout makes the global b-frag read byte-identical to the
// LDS read (1KB contiguous per wave). Drop LDS entirely: b-frags direct
// from L2. No barrier, no drain, LDS=0, VGPR ~90 -> 4-5 blocks/CU, compiler
// free to pipeline the fully-unrolled K-loop. Extra L2 read traffic 160MB
// aggregate (~4.6us at 34.5TB/s, overlapped) buys zero serialization.
// Packed offset for (row r, dim d): g=r>>4, rr=r&15, kb=d>>5, quad=(d>>3)&3,
// e=d&7 ->  g*5120 + kb*512 + quad*128 + rr*8 + e.

#define DD   300
#define WQ   16
#define NQ   1024         // B*Q
#define NL   8192
#define EPSV 1e-8f
#define GSTRIDE 5120      // elems per 16-row packed group (16*320)

typedef __bf16 bf16_t;
typedef __attribute__((ext_vector_type(8))) __bf16 bf16x8;
typedef __attribute__((ext_vector_type(4))) float f32x4;
typedef __attribute__((ext_vector_type(4))) int i32x4;

// ---------- P: fused q_e + l_e build -> packed layout + fp32 norms + flags ----------
__global__ __launch_bounds__(320) void build_ql(const float* __restrict__ emb,
                                                const int* __restrict__ queries,
                                                const int* __restrict__ labels,
                                                bf16_t* __restrict__ qep,
                                                bf16_t* __restrict__ lep,
                                                float* __restrict__ qn,
                                                float* __restrict__ lnrm,
                                                int* __restrict__ hasq,
                                                int* __restrict__ hasl) {
  const int blk = blockIdx.x;
  const int d = threadIdx.x;       // 0..319
  __shared__ float red[5];
  float v;

  const int kb = d >> 5, quad = (d >> 3) & 3, e = d & 7;
  const size_t poff = (size_t)kb * 512 + quad * 128 + e;   // + g*GSTRIDE + rr*8

  if (blk < NQ) {
    int n = 0;
    int idx[WQ];
#pragma unroll
    for (int w = 0; w < WQ; ++w) {
      idx[w] = queries[blk * WQ + w];
      n += (idx[w] != 0) ? 1 : 0;
    }
    float s = 0.f;
    if (d < DD) {
#pragma unroll
      for (int w = 0; w < WQ; ++w)
        s += emb[(size_t)idx[w] * DD + d];
    }
    const float qv = (d < DD) ? (s / (float)n) : 0.f;
    qep[(size_t)(blk >> 4) * GSTRIDE + (blk & 15) * 8 + poff] = (bf16_t)qv;
    v = qv;
    if (d == 0) hasq[blk] = (n != 0) ? 1 : 0;
  } else {
    const int l = blk - NQ;
    const int r = labels[l];
    float lv = 0.f;
    if (d < DD) lv = emb[(size_t)r * DD + d];
    lep[(size_t)(l >> 4) * GSTRIDE + (l & 15) * 8 + poff] = (bf16_t)lv;
    v = lv;
    if (d == 0) hasl[l] = (r != 0) ? 1 : 0;
  }

  v = v * v;
#pragma unroll
  for (int off = 32; off > 0; off >>= 1) v += __shfl_down(v, off);
  if ((threadIdx.x & 63) == 0) red[threadIdx.x >> 6] = v;
  __syncthreads();
  if (threadIdx.x == 0) {
    const float nrm = sqrtf(red[0] + red[1] + red[2] + red[3] + red[4]);
    if (blk < NQ) qn[blk] = nrm; else lnrm[blk - NQ] = nrm;
  }
}

// ---------- G: 128l x 64q block, 4 waves each 32l x 64q, NO LDS ----------
// b-frags read directly from packed qep in L2 (byte-identical addressing to
// the former LDS read, 1KB contiguous per wave). a-frags from packed lep,
// depth-1 double buffer. No barriers anywhere; straight-line load+MFMA.
// Bijective XCD swizzle: xcd owns 8 l-tiles x 16 q-tiles (~1.3MB L2 slice).
// Transposed product: A=le (m=l), B=qe (n=q); C: m=quad*4+reg (4 consecutive l),
// n=lane&15 (q) -> float4 stores to out[q][l] (4 quads of a wave complete
// 64B lines across 16 q-rows per store pair).
__global__ __launch_bounds__(256, 4) void gemm_cos(const bf16_t* __restrict__ qep,
                                                   const bf16_t* __restrict__ lep,
                                                   const float* __restrict__ qn,
                                                   const float* __restrict__ lnrm,
                                                   const int* __restrict__ hasq,
                                                   const int* __restrict__ hasl,
                                                   float* __restrict__ out) {
  const int bid = blockIdx.x;
  const int xcd = bid & 7;
  const int k   = bid >> 3;
  const int l0  = (xcd * 8 + (k & 7)) * 128;  // label tile (MFMA m)
  const int q0  = (k >> 3) * 64;              // query tile (MFMA n)
  const int wave = threadIdx.x >> 6;
  const int lane = threadIdx.x & 63;
  const int l16 = lane & 15;
  const int quad = lane >> 4;
  const int wl = wave * 32;         // this wave's l-offset within the block

  // frag base pointers (both packed; wave reads 1KB contiguous per frag row)
  const bf16_t* ap = lep + (size_t)((l0 >> 4) + wave * 2) * GSTRIDE + lane * 8;
  const bf16_t* bp = qep + (size_t)(q0 >> 4) * GSTRIDE + lane * 8;

  f32x4 acc[2][4] = {};   // [i over l-frags][j over q-frags]
  bf16x8 a[2][2];

#pragma unroll
  for (int i = 0; i < 2; ++i) a[0][i] = *(const bf16x8*)(ap + i * GSTRIDE);

#pragma unroll
  for (int kb = 0; kb < 10; ++kb) {
    const int cur = kb & 1, nxt = cur ^ 1;
    if (kb < 9) {
#pragma unroll
      for (int i = 0; i < 2; ++i)
        a[nxt][i] = *(const bf16x8*)(ap + i * GSTRIDE + (kb + 1) * 512);
    }
    bf16x8 b[4];
#pragma unroll
    for (int j = 0; j < 4; ++j)
      b[j] = *(const bf16x8*)(bp + (size_t)j * GSTRIDE + kb * 512);
#pragma unroll
    for (int i = 0; i < 2; ++i)
#pragma unroll
      for (int j = 0; j < 4; ++j)
        acc[i][j] = __builtin_amdgcn_mfma_f32_16x16x32_bf16(a[cur][i], b[j],
                                                            acc[i][j], 0, 0, 0);
  }

  // ---- epilogue: lane covers l = lb..lb+3 (consecutive), q = q0 + j*16 + l16 ----
  f32x4 lv[2];
  i32x4 hl[2];
#pragma unroll
  for (int i = 0; i < 2; ++i) {
    const int lb = l0 + wl + i * 16 + quad * 4;   // 16B-aligned
    lv[i] = *(const f32x4*)(lnrm + lb);
    hl[i] = *(const i32x4*)(hasl + lb);
  }

  float* const outm = out + (size_t)NQ * NL;
#pragma unroll
  for (int j = 0; j < 4; ++j) {
    const int q = q0 + j * 16 + l16;
    const float qv = qn[q];
    const int hq = hasq[q];
    const size_t rowb = (size_t)q * NL;
#pragma unroll
    for (int i = 0; i < 2; ++i) {
      const int lb = l0 + wl + i * 16 + quad * 4;
      f32x4 s, m;
#pragma unroll
      for (int r = 0; r < 4; ++r) {
        const float den = fmaxf(qv * lv[i][r], EPSV);
        s[r] = acc[i][j][r] * __builtin_amdgcn_rcpf(den);
        m[r] = (hq && hl[i][r]) ? 1.f : 0.f;
      }
      *(f32x4*)(out + rowb + lb) = s;
      *(f32x4*)(outm + rowb + lb) = m;
    }
  }
}

extern "C" void kernel_launch(void* const* d_in, const int* in_sizes, int n_in,
                              void* d_out, int out_size, void* d_ws, size_t ws_size,
                              hipStream_t stream) {
  const float* emb = (const float*)d_in[0];     // 50000 x 300 f32
  const int* queries = (const int*)d_in[1];     // 8*128*16 int32
  const int* labels = (const int*)d_in[2];      // 8192 int32

  char* ws = (char*)d_ws;
  bf16_t* qep  = (bf16_t*)(ws);                 // 1024*320*2  = 655360 B (packed)
  bf16_t* lep  = (bf16_t*)(ws + 655360);        // 8192*320*2  = 5242880 B (packed)
  float*  qn   = (float*) (ws + 5898240);       // 1024*4
  float*  lnrm = (float*) (ws + 5902336);       // 8192*4
  int*    hasq = (int*)   (ws + 5935104);       // 1024*4
  int*    hasl = (int*)   (ws + 5939200);       // 8192*4  (end ~5.95 MB)

  float* out = (float*)d_out;

  build_ql<<<NQ + NL, 320, 0, stream>>>(emb, queries, labels, qep, lep, qn, lnrm, hasq, hasl);
  gemm_cos<<<1024, 256, 0, stream>>>(qep, lep, qn, lnrm, hasq, hasl, out);
}

// Round 5
// 128.146 us; speedup vs baseline: 1.0112x; 1.0112x over previous
//
#include <hip/hip_runtime.h>
#include <hip/hip_bf16.h>

// Problem: V=50000, D=300, B=8, Q=128, W=16, L=8192
//   q_e[bq]   = sum_w emb[queries[bq,w]] / count(queries[bq,w]!=0)
//   sim[bq,l] = dot(q_e[bq], emb[labels[l]]) / max(|q_e[bq]|*|emb[labels[l]]|, 1e-8)
//   mask[bq,l]= (count!=0) && (labels[l]!=0)
// dtypes: emb float32, indices int32 (harness-converted), out float32.
// Output: sim (8,128,1,8192) then mask (8,128,1,8192) = 16,777,216 floats.
//
// History: R6 packed layout 153.9->129.7. R7 LDS-staged qe + dbl-buf a-frags
// = 125.8 (BEST). R8 FAIL 133.8 (full prefetch -> VGPR cliff). R9 XCD swizzle
// neutral. R10 64x64+2-gen 128.2. R11 no-LDS 129.6 (b-frag path matters; the
// R7 loop is locally optimal). Remaining un-attacked cost: the store tail --
// 64KB/block of output issued in ONE burst at kernel end with exactly 1 block
// generation -> ~10.7us/CU of exposed HBM write drain. Also R7 VGPR~130 was
// just over the 128 cliff (3 waves/SIMD -> 3 blocks/CU, not 4).
// R12 (this): keep R7 staging+kb-loop identical, but hoist the wave's two
// l-groups into an OUTER pass loop: per pass acc[4] (16 VGPR) for 16 l-rows,
// store, next pass. Pass-1 stores drain under pass-2 ds_read+MFMA (halved
// exposed tail); VGPR ~100 < 128 -> true 4 blocks/CU (launch_bounds(256,4)).
// Cost: b ds_reads x2 (LDS BW has 2x headroom).
// Packed offset for (row r, dim d): g=r>>4, rr=r&15, kb=d>>5, quad=(d>>3)&3,
// e=d&7 ->  g*5120 + kb*512 + quad*128 + rr*8 + e.

#define DD   300
#define WQ   16
#define NQ   1024         // B*Q
#define NL   8192
#define EPSV 1e-8f
#define GSTRIDE 5120      // elems per 16-row packed group (16*320)

typedef __bf16 bf16_t;
typedef __attribute__((ext_vector_type(8))) __bf16 bf16x8;
typedef __attribute__((ext_vector_type(4))) float f32x4;
typedef __attribute__((ext_vector_type(4))) int i32x4;

// ---------- P: fused q_e + l_e build -> packed layout + fp32 norms + flags ----------
__global__ __launch_bounds__(320) void build_ql(const float* __restrict__ emb,
                                                const int* __restrict__ queries,
                                                const int* __restrict__ labels,
                                                bf16_t* __restrict__ qep,
                                                bf16_t* __restrict__ lep,
                                                float* __restrict__ qn,
                                                float* __restrict__ lnrm,
                                                int* __restrict__ hasq,
                                                int* __restrict__ hasl) {
  const int blk = blockIdx.x;
  const int d = threadIdx.x;       // 0..319
  __shared__ float red[5];
  float v;

  const int kb = d >> 5, quad = (d >> 3) & 3, e = d & 7;
  const size_t poff = (size_t)kb * 512 + quad * 128 + e;   // + g*GSTRIDE + rr*8

  if (blk < NQ) {
    int n = 0;
    int idx[WQ];
#pragma unroll
    for (int w = 0; w < WQ; ++w) {
      idx[w] = queries[blk * WQ + w];
      n += (idx[w] != 0) ? 1 : 0;
    }
    float s = 0.f;
    if (d < DD) {
#pragma unroll
      for (int w = 0; w < WQ; ++w)
        s += emb[(size_t)idx[w] * DD + d];
    }
    const float qv = (d < DD) ? (s / (float)n) : 0.f;
    qep[(size_t)(blk >> 4) * GSTRIDE + (blk & 15) * 8 + poff] = (bf16_t)qv;
    v = qv;
    if (d == 0) hasq[blk] = (n != 0) ? 1 : 0;
  } else {
    const int l = blk - NQ;
    const int r = labels[l];
    float lv = 0.f;
    if (d < DD) lv = emb[(size_t)r * DD + d];
    lep[(size_t)(l >> 4) * GSTRIDE + (l & 15) * 8 + poff] = (bf16_t)lv;
    v = lv;
    if (d == 0) hasl[l] = (r != 0) ? 1 : 0;
  }

  v = v * v;
#pragma unroll
  for (int off = 32; off > 0; off >>= 1) v += __shfl_down(v, off);
  if ((threadIdx.x & 63) == 0) red[threadIdx.x >> 6] = v;
  __syncthreads();
  if (threadIdx.x == 0) {
    const float nrm = sqrtf(red[0] + red[1] + red[2] + red[3] + red[4]);
    if (blk < NQ) qn[blk] = nrm; else lnrm[blk - NQ] = nrm;
  }
}

// ---------- G: 128l x 64q block, 4 waves; TWO serial 16l passes per wave ----------
// qe tile (64q x 320 packed = 40KB) staged to LDS once (global_load_lds w=16,
// one barrier); per pass: kb-loop (depth-1 dbl-buffered a-frag from packed
// lep + 4 conflict-free ds_read_b128 b-frags + 4 MFMA), then store that
// pass's 16 l-rows. Pass-1 stores overlap pass-2 compute; acc[4]=16 VGPR
// keeps total ~100 -> 4 blocks/CU (16 waves, the real latency hiding).
// Bijective XCD swizzle. Transposed product: A=le (m=l), B=qe (n=q);
// C: m=quad*4+reg (4 consecutive l), n=lane&15 (q) -> float4 stores out[q][l].
__global__ __launch_bounds__(256, 4) void gemm_cos(const bf16_t* __restrict__ qep,
                                                   const bf16_t* __restrict__ lep,
                                                   const float* __restrict__ qn,
                                                   const float* __restrict__ lnrm,
                                                   const int* __restrict__ hasq,
                                                   const int* __restrict__ hasl,
                                                   float* __restrict__ out) {
  const int bid = blockIdx.x;
  const int xcd = bid & 7;
  const int k   = bid >> 3;
  const int l0  = (xcd * 8 + (k & 7)) * 128;  // label tile (MFMA m)
  const int q0  = (k >> 3) * 64;              // query tile (MFMA n)
  const int wave = threadIdx.x >> 6;
  const int lane = threadIdx.x & 63;
  const int l16 = lane & 15;
  const int quad = lane >> 4;
  const int wl = wave * 32;         // this wave's l-offset within the block

  __shared__ __align__(16) bf16_t qls[4 * GSTRIDE];   // 20480 elems = 40 KB

  // ---- stage packed qe tile (4 consecutive groups, fully contiguous) ----
  {
    const char* gsrc = (const char*)(qep + (size_t)(q0 >> 4) * GSTRIDE);
    char* lbase = (char*)qls;
#pragma unroll
    for (int t = 0; t < 10; ++t) {
      const int boff = (t * 256 + threadIdx.x) * 16;
      __builtin_amdgcn_global_load_lds(
          (const __attribute__((address_space(1))) void*)(gsrc + boff),
          (__attribute__((address_space(3))) void*)(lbase + boff),
          16, 0, 0);
    }
  }

  // a-frag base (this wave's two 16-row l-groups; pass i uses +i*GSTRIDE)
  const bf16_t* ap = lep + (size_t)((l0 >> 4) + wave * 2) * GSTRIDE + lane * 8;

  bf16x8 a[2];
  a[0] = *(const bf16x8*)ap;        // pass-0 first frag (drains under barrier)

  float* const outm = out + (size_t)NQ * NL;

  __syncthreads();                  // LDS tile ready (drains global_load_lds)

#pragma unroll
  for (int i = 0; i < 2; ++i) {
    const bf16_t* api = ap + (size_t)i * GSTRIDE;
    f32x4 acc[4] = {};

#pragma unroll
    for (int kb = 0; kb < 10; ++kb) {
      const int cur = kb & 1, nxt = cur ^ 1;
      if (kb < 9) a[nxt] = *(const bf16x8*)(api + (kb + 1) * 512);
      bf16x8 b[4];
#pragma unroll
      for (int j = 0; j < 4; ++j)
        b[j] = *(const bf16x8*)(qls + (size_t)j * GSTRIDE + kb * 512 + lane * 8);
#pragma unroll
      for (int j = 0; j < 4; ++j)
        acc[j] = __builtin_amdgcn_mfma_f32_16x16x32_bf16(a[cur], b[j], acc[j], 0, 0, 0);
    }

    // prefetch next pass's first a-frag so its latency hides under our stores
    if (i == 0) a[0] = *(const bf16x8*)(ap + GSTRIDE);

    // ---- epilogue for this pass: l = lb..lb+3, q = q0 + j*16 + l16 ----
    const int lb = l0 + wl + i * 16 + quad * 4;      // 16B-aligned
    const f32x4 lv = *(const f32x4*)(lnrm + lb);
    const i32x4 hl = *(const i32x4*)(hasl + lb);
#pragma unroll
    for (int j = 0; j < 4; ++j) {
      const int q = q0 + j * 16 + l16;
      const float qv = qn[q];
      const int hq = hasq[q];
      const size_t rowb = (size_t)q * NL;
      f32x4 s, m;
#pragma unroll
      for (int r = 0; r < 4; ++r) {
        const float den = fmaxf(qv * lv[r], EPSV);
        s[r] = acc[j][r] * __builtin_amdgcn_rcpf(den);
        m[r] = (hq && hl[r]) ? 1.f : 0.f;
      }
      *(f32x4*)(out + rowb + lb) = s;
      *(f32x4*)(outm + rowb + lb) = m;
    }
  }
}

extern "C" void kernel_launch(void* const* d_in, const int* in_sizes, int n_in,
                              void* d_out, int out_size, void* d_ws, size_t ws_size,
                              hipStream_t stream) {
  const float* emb = (const float*)d_in[0];     // 50000 x 300 f32
  const int* queries = (const int*)d_in[1];     // 8*128*16 int32
  const int* labels = (const int*)d_in[2];      // 8192 int32

  char* ws = (char*)d_ws;
  bf16_t* qep  = (bf16_t*)(ws);                 // 1024*320*2  = 655360 B (packed)
  bf16_t* lep  = (bf16_t*)(ws + 655360);        // 8192*320*2  = 5242880 B (packed)
  float*  qn   = (float*) (ws + 5898240);       // 1024*4
  float*  lnrm = (float*) (ws + 5902336);       // 8192*4
  int*    hasq = (int*)   (ws + 5935104);       // 1024*4
  int*    hasl = (int*)   (ws + 5939200);       // 8192*4  (end ~5.95 MB)

  float* out = (float*)d_out;

  build_ql<<<NQ + NL, 320, 0, stream>>>(emb, queries, labels, qep, lep, qn, lnrm, hasq, hasl);
  gemm_cos<<<1024, 256, 0, stream>>>(qep, lep, qn, lnrm, hasq, hasl, out);
}

// Round 6
// 119.975 us; speedup vs baseline: 1.0800x; 1.0681x over previous
//
#include <hip/hip_runtime.h>
#include <hip/hip_bf16.h>

// Problem: V=50000, D=300, B=8, Q=128, W=16, L=8192
//   q_e[bq]   = sum_w emb[queries[bq,w]] / count(queries[bq,w]!=0)
//   sim[bq,l] = dot(q_e[bq], emb[labels[l]]) / max(|q_e[bq]|*|emb[labels[l]]|, 1e-8)
//   mask[bq,l]= (count!=0) && (labels[l]!=0)
// dtypes: emb float32, indices int32 (harness-converted), out float32.
// Output: sim (8,128,1,8192) then mask (8,128,1,8192) = 16,777,216 floats.
//
// History: R6 packed layout 153.9->129.7. R7 LDS-staged qe + dbl-buf a-frags
// = 125.8 (BEST). R8 FAIL 133.8 (full prefetch -> VGPR cliff). R9 swizzle
// neutral 126.4. R10 64x64+2gen 128.2. R11 no-LDS 129.6. R12 pass-split
// 128.1. FIVE gemm restructurings neutral-to-negative => R7 gemm is locally
// optimal; frozen verbatim below (2D grid, no swizzle).
// R13 (this): only un-attacked component is build_ql's label half: 8192
// single-label blocks = one idx-load + one gather latency chain each, ~36
// blocks/CU = ~6 serial latency rounds. Batch 8 labels/block (8 independent
// gather chains amortize the latency; 8 norm reductions ride one shfl tree);
// grid 9216 -> 2048 blocks. Same traffic, ~4x fewer latency rounds.
// Composite budget: 2x42us harness fills + build + gemm; region floor ~102us
// at 6.3TB/s. If this lands >=125 flat, declare roofline.
// Packed offset for (row r, dim d): g=r>>4, rr=r&15, kb=d>>5, quad=(d>>3)&3,
// e=d&7 ->  g*5120 + kb*512 + quad*128 + rr*8 + e.

#define DD   300
#define WQ   16
#define NQ   1024         // B*Q
#define NL   8192
#define GB   8            // labels per build block
#define EPSV 1e-8f
#define GSTRIDE 5120      // elems per 16-row packed group (16*320)

typedef __bf16 bf16_t;
typedef __attribute__((ext_vector_type(8))) __bf16 bf16x8;
typedef __attribute__((ext_vector_type(4))) float f32x4;
typedef __attribute__((ext_vector_type(4))) int i32x4;

// ---------- P: fused q_e + l_e build -> packed layout + fp32 norms + flags ----------
// Query blocks (blk < NQ): one query, 16 gathers/thread (amortized).
// Label blocks: GB=8 labels each, 8 gathers/thread + 8 parallel shfl-tree
// norm reductions -- amortizes the idx-load + gather latency chain that made
// single-label blocks latency-round-bound.
__global__ __launch_bounds__(320) void build_ql(const float* __restrict__ emb,
                                                const int* __restrict__ queries,
                                                const int* __restrict__ labels,
                                                bf16_t* __restrict__ qep,
                                                bf16_t* __restrict__ lep,
                                                float* __restrict__ qn,
                                                float* __restrict__ lnrm,
                                                int* __restrict__ hasq,
                                                int* __restrict__ hasl) {
  const int blk = blockIdx.x;
  const int d = threadIdx.x;       // 0..319
  __shared__ float red[5 * GB];

  const int kb = d >> 5, quad = (d >> 3) & 3, e = d & 7;
  const size_t poff = (size_t)kb * 512 + quad * 128 + e;   // + g*GSTRIDE + rr*8

  if (blk < NQ) {
    int n = 0;
    int idx[WQ];
#pragma unroll
    for (int w = 0; w < WQ; ++w) {
      idx[w] = queries[blk * WQ + w];
      n += (idx[w] != 0) ? 1 : 0;
    }
    float s = 0.f;
    if (d < DD) {
#pragma unroll
      for (int w = 0; w < WQ; ++w)
        s += emb[(size_t)idx[w] * DD + d];
    }
    const float qv = (d < DD) ? (s / (float)n) : 0.f;
    qep[(size_t)(blk >> 4) * GSTRIDE + (blk & 15) * 8 + poff] = (bf16_t)qv;
    if (d == 0) hasq[blk] = (n != 0) ? 1 : 0;

    float v = qv * qv;
#pragma unroll
    for (int off = 32; off > 0; off >>= 1) v += __shfl_down(v, off);
    if ((threadIdx.x & 63) == 0) red[threadIdx.x >> 6] = v;
    __syncthreads();
    if (threadIdx.x == 0)
      qn[blk] = sqrtf(red[0] + red[1] + red[2] + red[3] + red[4]);
  } else {
    const int lb0 = (blk - NQ) * GB;
    int idxs[GB];
    float lv[GB];
#pragma unroll
    for (int g = 0; g < GB; ++g) idxs[g] = labels[lb0 + g];
#pragma unroll
    for (int g = 0; g < GB; ++g)
      lv[g] = (d < DD) ? emb[(size_t)idxs[g] * DD + d] : 0.f;
#pragma unroll
    for (int g = 0; g < GB; ++g) {
      const int l = lb0 + g;
      lep[(size_t)(l >> 4) * GSTRIDE + (l & 15) * 8 + poff] = (bf16_t)lv[g];
    }
    float vg[GB];
#pragma unroll
    for (int g = 0; g < GB; ++g) vg[g] = lv[g] * lv[g];
#pragma unroll
    for (int off = 32; off > 0; off >>= 1) {
#pragma unroll
      for (int g = 0; g < GB; ++g) vg[g] += __shfl_down(vg[g], off);
    }
    if ((threadIdx.x & 63) == 0) {
#pragma unroll
      for (int g = 0; g < GB; ++g) red[(threadIdx.x >> 6) * GB + g] = vg[g];
    }
    __syncthreads();
    if (threadIdx.x < GB) {
      const int g = threadIdx.x;
      lnrm[lb0 + g] = sqrtf(red[0 * GB + g] + red[1 * GB + g] + red[2 * GB + g] +
                            red[3 * GB + g] + red[4 * GB + g]);
      hasl[lb0 + g] = (idxs[g] != 0) ? 1 : 0;
    }
  }
}

// ---------- G: 128l x 64q block, 4 waves each 32l x 64q (R7 verbatim) ----------
// qe tile (64q x 320 packed = 40KB) staged to LDS once (global_load_lds w=16,
// one barrier), b-frags via conflict-free ds_read_b128; only 2 dbl-buffered
// global a-frag loads per kb. Kills the 4x intra-block qe redundancy.
// Transposed product: A=le (m=l), B=qe (n=q); C: m=quad*4+reg (4 consecutive l),
// n=lane&15 (q) -> float4 stores to out[q][l]. 1024 blocks = 4/CU (LDS-capped).
__global__ __launch_bounds__(256) void gemm_cos(const bf16_t* __restrict__ qep,
                                                const bf16_t* __restrict__ lep,
                                                const float* __restrict__ qn,
                                                const float* __restrict__ lnrm,
                                                const int* __restrict__ hasq,
                                                const int* __restrict__ hasl,
                                                float* __restrict__ out) {
  const int l0 = blockIdx.x * 128;  // label tile (MFMA m)
  const int q0 = blockIdx.y * 64;   // query tile (MFMA n)
  const int wave = threadIdx.x >> 6;
  const int lane = threadIdx.x & 63;
  const int l16 = lane & 15;
  const int quad = lane >> 4;
  const int wl = wave * 32;         // this wave's l-offset within the block

  __shared__ __align__(16) bf16_t qls[4 * GSTRIDE];   // 20480 elems = 40 KB

  // ---- stage packed qe tile (4 consecutive groups, fully contiguous) ----
  {
    const char* gsrc = (const char*)(qep + (size_t)(q0 >> 4) * GSTRIDE);
    char* lbase = (char*)qls;
#pragma unroll
    for (int t = 0; t < 10; ++t) {
      const int boff = (t * 256 + threadIdx.x) * 16;
      __builtin_amdgcn_global_load_lds(
          (const __attribute__((address_space(1))) void*)(gsrc + boff),
          (__attribute__((address_space(3))) void*)(lbase + boff),
          16, 0, 0);
    }
  }

  // a-frag base (this wave's two 16-row l-groups)
  const bf16_t* ap = lep + (size_t)((l0 >> 4) + wave * 2) * GSTRIDE + lane * 8;

  f32x4 acc[2][4] = {};   // [i over l-frags][j over q-frags]
  bf16x8 a[2][2];

  __syncthreads();        // LDS tile ready (also drains global_load_lds via barrier wait)

#pragma unroll
  for (int i = 0; i < 2; ++i) a[0][i] = *(const bf16x8*)(ap + i * GSTRIDE);

#pragma unroll
  for (int kb = 0; kb < 10; ++kb) {
    const int cur = kb & 1, nxt = cur ^ 1;
    if (kb < 9) {
#pragma unroll
      for (int i = 0; i < 2; ++i)
        a[nxt][i] = *(const bf16x8*)(ap + i * GSTRIDE + (kb + 1) * 512);
    }
    bf16x8 b[4];
#pragma unroll
    for (int j = 0; j < 4; ++j)
      b[j] = *(const bf16x8*)(qls + (size_t)j * GSTRIDE + kb * 512 + lane * 8);
#pragma unroll
    for (int i = 0; i < 2; ++i)
#pragma unroll
      for (int j = 0; j < 4; ++j)
        acc[i][j] = __builtin_amdgcn_mfma_f32_16x16x32_bf16(a[cur][i], b[j],
                                                            acc[i][j], 0, 0, 0);
  }

  // ---- epilogue: lane covers l = lb..lb+3 (consecutive), q = q0 + j*16 + l16 ----
  float lv[2][4];
  int hl[2][4];
#pragma unroll
  for (int i = 0; i < 2; ++i) {
    const int lb = l0 + wl + i * 16 + quad * 4;
#pragma unroll
    for (int r = 0; r < 4; ++r) {
      lv[i][r] = lnrm[lb + r];
      hl[i][r] = hasl[lb + r];
    }
  }

  float* const outm = out + (size_t)NQ * NL;
#pragma unroll
  for (int j = 0; j < 4; ++j) {
    const int q = q0 + j * 16 + l16;
    const float qv = qn[q];
    const int hq = hasq[q];
    const size_t rowb = (size_t)q * NL;
#pragma unroll
    for (int i = 0; i < 2; ++i) {
      const int lb = l0 + wl + i * 16 + quad * 4;
      f32x4 s, m;
#pragma unroll
      for (int r = 0; r < 4; ++r) {
        const float den = fmaxf(qv * lv[i][r], EPSV);
        s[r] = acc[i][j][r] * __builtin_amdgcn_rcpf(den);
        m[r] = (hq && hl[i][r]) ? 1.f : 0.f;
      }
      *(f32x4*)(out + rowb + lb) = s;
      *(f32x4*)(outm + rowb + lb) = m;
    }
  }
}

extern "C" void kernel_launch(void* const* d_in, const int* in_sizes, int n_in,
                              void* d_out, int out_size, void* d_ws, size_t ws_size,
                              hipStream_t stream) {
  const float* emb = (const float*)d_in[0];     // 50000 x 300 f32
  const int* queries = (const int*)d_in[1];     // 8*128*16 int32
  const int* labels = (const int*)d_in[2];      // 8192 int32

  char* ws = (char*)d_ws;
  bf16_t* qep  = (bf16_t*)(ws);                 // 1024*320*2  = 655360 B (packed)
  bf16_t* lep  = (bf16_t*)(ws + 655360);        // 8192*320*2  = 5242880 B (packed)
  float*  qn   = (float*) (ws + 5898240);       // 1024*4
  float*  lnrm = (float*) (ws + 5902336);       // 8192*4
  int*    hasq = (int*)   (ws + 5935104);       // 1024*4
  int*    hasl = (int*)   (ws + 5939200);       // 8192*4  (end ~5.95 MB)

  float* out = (float*)d_out;

  build_ql<<<NQ + NL / GB, 320, 0, stream>>>(emb, queries, labels, qep, lep, qn, lnrm, hasq, hasl);
  gemm_cos<<<dim3(NL / 128, NQ / 64), 256, 0, stream>>>(qep, lep, qn, lnrm, hasq, hasl, out);
}